// Round 8
// baseline (249.676 us; speedup 1.0000x reference)
//
#include <hip/hip_runtime.h>
#include <math.h>

#define SEQ 2048
#define DIM 1024
#define NH 16
#define DPH 64
#define MTOT 4096  // BS2 * SEQ

typedef __attribute__((ext_vector_type(8))) short bf16x8;
typedef __attribute__((ext_vector_type(4))) float f32x4;
typedef __attribute__((ext_vector_type(16))) float f32x16;
typedef __attribute__((ext_vector_type(4))) unsigned int u32x4;

__device__ __forceinline__ unsigned short f2bf(float f) {
    unsigned int u = __float_as_uint(f);
    return (unsigned short)((u + 0x7FFFu + ((u >> 16) & 1u)) >> 16);
}
__device__ __forceinline__ float bf2f(unsigned short h) {
    return __uint_as_float(((unsigned int)h) << 16);
}

__device__ __forceinline__ void stage16(const void* g, void* lds) {
    __builtin_amdgcn_global_load_lds((const __attribute__((address_space(1))) void*)g,
                                     (__attribute__((address_space(3))) void*)lds,
                                     16, 0, 0);
}

__device__ __forceinline__ unsigned cvtpk(float lo, float hi) {
    unsigned w;
    asm("v_cvt_pk_bf16_f32 %0, %1, %2" : "=v"(w) : "v"(lo), "v"(hi));
    return w;
}
// v_permlane32_swap_b32 A, B:  A' = {A_lo, B_lo}, B' = {A_hi, B_hi}
__device__ __forceinline__ void plswap(unsigned &a, unsigned &b) {
    asm("v_permlane32_swap_b32 %0, %1" : "+v"(a), "+v"(b));
}

// XCD-aware bijective remap (nb % 8 == 0). Dispatch order: x fastest.
__device__ __forceinline__ void xcd_remap(int gx, int gy, int gz,
                                          int &x, int &y, int &z)
{
    const int h = (blockIdx.z * gy + blockIdx.y) * gx + blockIdx.x;
    const int nb = gx * gy * gz;
    const int chunk = nb >> 3;
    const int l = (h & 7) * chunk + (h >> 3);
    const int P = gx * gz;
    y = l / P;
    const int r = l - y * P;
    z = r / gx;
    x = r - z * gx;
}

// ---------------- prep: cast x to bf16 ----------------
__global__ __launch_bounds__(256) void cast_x(const float* __restrict__ X,
                                              unsigned short* __restrict__ Xb)
{
    size_t i = (size_t)blockIdx.x * 256 + threadIdx.x;
    float4 v = *(const float4*)&X[i * 4];
    ushort4 o;
    o.x = f2bf(v.x); o.y = f2bf(v.y); o.z = f2bf(v.z); o.w = f2bf(v.w);
    *(ushort4*)&Xb[i * 4] = o;
}

// ---------------- prep: transpose-cast W [k][n] f32 -> Wt [n][k] bf16 ----------------
__global__ __launch_bounds__(256) void prep_w(
    const float* __restrict__ Wq, const float* __restrict__ Wk,
    const float* __restrict__ Wv, const float* __restrict__ Wo,
    unsigned short* __restrict__ Wqt, unsigned short* __restrict__ Wkt,
    unsigned short* __restrict__ Wvt, unsigned short* __restrict__ Wot)
{
    const float* W; unsigned short* Wt;
    switch (blockIdx.z) {
        case 0: W = Wq; Wt = Wqt; break;
        case 1: W = Wk; Wt = Wkt; break;
        case 2: W = Wv; Wt = Wvt; break;
        default: W = Wo; Wt = Wot; break;
    }
    __shared__ float T[32][33];
    const int t = threadIdx.x;
    const int kt0 = blockIdx.y * 32;
    const int nt0 = blockIdx.x * 32;
    const int r = t >> 3, c4 = (t & 7) * 4;
    float4 v = *(const float4*)&W[(size_t)(kt0 + r) * DIM + nt0 + c4];
    T[r][c4 + 0] = v.x; T[r][c4 + 1] = v.y; T[r][c4 + 2] = v.z; T[r][c4 + 3] = v.w;
    __syncthreads();
    ushort4 o;
    o.x = f2bf(T[c4 + 0][r]);
    o.y = f2bf(T[c4 + 1][r]);
    o.z = f2bf(T[c4 + 2][r]);
    o.w = f2bf(T[c4 + 3][r]);
    *(ushort4*)&Wt[(size_t)(nt0 + r) * DIM + kt0 + c4] = o;
}

// ---------------- pack mask bits ----------------
__global__ __launch_bounds__(256) void pack_mask(const int* __restrict__ mask,
                                                 unsigned long long* __restrict__ MB)
{
    const int w = blockIdx.x * 4 + (threadIdx.x >> 6);
    const int lane = threadIdx.x & 63;
    const int b = w >> 5, kt = w & 31;
    int m = mask[b * SEQ + kt * 64 + lane];
    unsigned long long bits = __ballot(m != 0);
    if (lane == 0) MB[w] = bits;
}

// ---------------- bf16 MFMA GEMM core: 3-deep staging ring, counted vmcnt ----------------
// mode 0: normalized bf16 out (per-head L2 norm; qs factor)
// mode 1: bf16 transposed V out [b,h,d,seq]
// mode 2: fp32 out + bias
__device__ __forceinline__ void gemm_core(
    const unsigned short* __restrict__ Ab, const unsigned short* __restrict__ Bt,
    const float* __restrict__ bias, unsigned short* __restrict__ Cb,
    float* __restrict__ Cf, int mode, int bx, int by, float qs)
{
    __shared__ __align__(16) unsigned short As[3 * 4096];  // 3-buffer ring, 24 KB
    __shared__ __align__(16) unsigned short Bs[3 * 4096];  // 24 KB

    const int tid = threadIdx.x;
    const int l = tid & 63;
    const int w = tid >> 6;
    const int wm = w >> 1, wn = w & 1;
    const int lr = l & 15, lg = l >> 4;
    const int bm = by * 128;
    const int bn = bx * 128;

    const unsigned short* a_src0 = Ab + (size_t)(bm + (2 * w) * 16 + lr) * DIM + lg * 8;
    const unsigned short* a_src1 = Ab + (size_t)(bm + (2 * w + 1) * 16 + lr) * DIM + lg * 8;
    const unsigned short* b_src0 = Bt + (size_t)(bn + (2 * w) * 16 + lr) * DIM + lg * 8;
    const unsigned short* b_src1 = Bt + (size_t)(bn + (2 * w + 1) * 16 + lr) * DIM + lg * 8;

    const int s0 = (2 * w) * 512, s1 = (2 * w + 1) * 512;

    f32x4 acc[4][4];
#pragma unroll
    for (int i = 0; i < 4; ++i)
#pragma unroll
        for (int j = 0; j < 4; ++j) acc[i][j] = (f32x4){0.f, 0.f, 0.f, 0.f};

    // prologue: stage tiles 0,1 into ring slots 0,1 (8 loads/wave in flight)
    stage16(a_src0, &As[s0]);
    stage16(a_src1, &As[s1]);
    stage16(b_src0, &Bs[s0]);
    stage16(b_src1, &Bs[s1]);
    stage16(a_src0 + 32, &As[4096 + s0]);
    stage16(a_src1 + 32, &As[4096 + s1]);
    stage16(b_src0 + 32, &Bs[4096 + s0]);
    stage16(b_src1 + 32, &Bs[4096 + s1]);

    int cur = 0;   // ring slot of tile t
    int nx2 = 2;   // ring slot of tile t+2
    for (int t = 0; t < 32; ++t) {
        // tile t's 4 loads are the oldest; allow tile t+1's 4 to stay in flight.
        if (t == 31) asm volatile("s_waitcnt vmcnt(0)" ::: "memory");
        else         asm volatile("s_waitcnt vmcnt(4)" ::: "memory");
        __builtin_amdgcn_s_barrier();  // all waves: tile t landed; compute(t-1) done

        if (t + 2 < 32) {  // stage tile t+2 into the slot consumed at t-1
            const int kk = (t + 2) * 32;
            stage16(a_src0 + kk, &As[nx2 * 4096 + s0]);
            stage16(a_src1 + kk, &As[nx2 * 4096 + s1]);
            stage16(b_src0 + kk, &Bs[nx2 * 4096 + s0]);
            stage16(b_src1 + kk, &Bs[nx2 * 4096 + s1]);
        }

        const unsigned short* Ap = &As[cur * 4096];
        const unsigned short* Bp = &Bs[cur * 4096];
        bf16x8 aF[4], bF[4];
#pragma unroll
        for (int i = 0; i < 4; ++i) {
            aF[i] = *(const bf16x8*)&Ap[(wm * 4 + i) * 512 + l * 8];
            bF[i] = *(const bf16x8*)&Bp[(wn * 4 + i) * 512 + l * 8];
        }
#pragma unroll
        for (int i = 0; i < 4; ++i)
#pragma unroll
            for (int j = 0; j < 4; ++j)
                acc[i][j] = __builtin_amdgcn_mfma_f32_16x16x32_bf16(aF[i], bF[j], acc[i][j], 0, 0, 0);

        cur = (cur == 2) ? 0 : cur + 1;
        nx2 = (nx2 == 2) ? 0 : nx2 + 1;
    }

    // bias add (bias[n] per column)
    float bvj[4];
#pragma unroll
    for (int j = 0; j < 4; ++j) bvj[j] = bias[bn + wn * 64 + j * 16 + lr];
#pragma unroll
    for (int i = 0; i < 4; ++i)
#pragma unroll
        for (int j = 0; j < 4; ++j)
#pragma unroll
            for (int p = 0; p < 4; ++p) acc[i][j][p] += bvj[j];

    if (mode == 0) {
        // fused per-head L2 norm: head = 64 cols = j regs x 16 lr lanes (within wave)
#pragma unroll
        for (int i = 0; i < 4; ++i) {
            float scl[4];
#pragma unroll
            for (int p = 0; p < 4; ++p) {
                float s = 0.f;
#pragma unroll
                for (int j = 0; j < 4; ++j) s = fmaf(acc[i][j][p], acc[i][j][p], s);
                s += __shfl_xor(s, 1);
                s += __shfl_xor(s, 2);
                s += __shfl_xor(s, 4);
                s += __shfl_xor(s, 8);
                scl[p] = qs / fmaxf(sqrtf(s), 1e-12f);
            }
            const int m0 = bm + wm * 64 + i * 16 + lg * 4;
#pragma unroll
            for (int j = 0; j < 4; ++j) {
                const int n = bn + wn * 64 + j * 16 + lr;
#pragma unroll
                for (int p = 0; p < 4; ++p)
                    Cb[(size_t)(m0 + p) * DIM + n] = f2bf(acc[i][j][p] * scl[p]);
            }
        }
    } else if (mode == 1) {
#pragma unroll
        for (int i = 0; i < 4; ++i) {
            const int m0 = bm + wm * 64 + i * 16 + lg * 4;
            const int b = m0 >> 11, s = m0 & 2047;
#pragma unroll
            for (int j = 0; j < 4; ++j) {
                const int n = bn + wn * 64 + j * 16 + lr;
                const int h = n >> 6, d = n & 63;
                ushort4 o;
                o.x = f2bf(acc[i][j][0]);
                o.y = f2bf(acc[i][j][1]);
                o.z = f2bf(acc[i][j][2]);
                o.w = f2bf(acc[i][j][3]);
                *(ushort4*)&Cb[((size_t)((b * NH + h) * DPH + d)) * SEQ + s] = o;
            }
        }
    } else {
#pragma unroll
        for (int i = 0; i < 4; ++i) {
            const int m0 = bm + wm * 64 + i * 16 + lg * 4;
#pragma unroll
            for (int j = 0; j < 4; ++j) {
                const int n = bn + wn * 64 + j * 16 + lr;
#pragma unroll
                for (int p = 0; p < 4; ++p)
                    Cf[(size_t)(m0 + p) * DIM + n] = acc[i][j][p];
            }
        }
    }
}

__global__ __launch_bounds__(256) void qkv_gemm(
    const unsigned short* __restrict__ Xb,
    const unsigned short* __restrict__ Wqt, const unsigned short* __restrict__ Wkt,
    const unsigned short* __restrict__ Wvt,
    const float* __restrict__ bq, const float* __restrict__ bk, const float* __restrict__ bv,
    const float* __restrict__ scale_p,
    unsigned short* __restrict__ Qb, unsigned short* __restrict__ Kb,
    unsigned short* __restrict__ Vtb)
{
    int x, y, z;
    xcd_remap(8, 32, 3, x, y, z);
    if (z == 0)
        gemm_core(Xb, Wqt, bq, Qb, nullptr, 0, x, y, scale_p[0] * 1.44269504088896340736f);
    else if (z == 1)
        gemm_core(Xb, Wkt, bk, Kb, nullptr, 0, x, y, 1.0f);
    else
        gemm_core(Xb, Wvt, bv, Vtb, nullptr, 1, x, y, 1.0f);
}

__global__ __launch_bounds__(256) void o_gemm(
    const unsigned short* __restrict__ Ab, const unsigned short* __restrict__ Wot,
    const float* __restrict__ bo, float* __restrict__ Out)
{
    int x, y, z;
    xcd_remap(8, 32, 1, x, y, z);
    gemm_core(Ab, Wot, bo, nullptr, Out, 2, x, y, 1.0f);
}

// ---------------- flash attention, 32x32x16 MFMA, swapped QK^T, no-max softmax ----------------
__global__ __launch_bounds__(256) void attn(
    const unsigned short* __restrict__ Qb, const unsigned short* __restrict__ Kb,
    const unsigned short* __restrict__ Vtb, const unsigned long long* __restrict__ MB,
    unsigned short* __restrict__ CTXb)
{
    __shared__ __align__(16) unsigned short Ks[2][4096];   // [key64][d64] swizzled
    __shared__ __align__(16) unsigned short Vts[2][4096];  // [d64][key64] swizzled

    const int tid = threadIdx.x;
    const int l = tid & 63;
    const int w = tid >> 6;
    const int l31 = l & 31;
    const int hi = l >> 5;

    // XCD remap: group the 16 q-tiles of each (head,batch) on one XCD
    int qt, h, b;
    {
        const int hh = (blockIdx.z * 16 + blockIdx.y) * 16 + blockIdx.x;
        const int ll = (hh & 7) * 64 + (hh >> 3);
        qt = ll & 15;
        const int g = ll >> 4;
        h = g & 15;
        b = g >> 4;
    }

    const size_t qrow = (size_t)(b * SEQ + qt * 128 + w * 32 + l31);
    bf16x8 qf[4];
#pragma unroll
    for (int df = 0; df < 4; ++df)
        qf[df] = *(const bf16x8*)&Qb[qrow * DIM + h * DPH + df * 16 + hi * 8];

    const int sub = l >> 3, ss = (l & 7) ^ sub;
    const unsigned short* Kptr  = Kb  + (size_t)(b * SEQ) * DIM + h * DPH;
    const unsigned short* Vtptr = Vtb + ((size_t)(b * NH + h) * DPH) * SEQ;
    const unsigned long long* mbp = MB + b * 32;

    f32x16 ctx0 = {}, ctx1 = {};
    float lsum = 0.f;

    {
        const int r0 = w * 16, r1 = w * 16 + 8;
        stage16(Kptr + (size_t)(r0 + sub) * DIM + ss * 8, &Ks[0][r0 * 64]);
        stage16(Kptr + (size_t)(r1 + sub) * DIM + ss * 8, &Ks[0][r1 * 64]);
        stage16(Vtptr + (size_t)(r0 + sub) * SEQ + ss * 8, &Vts[0][r0 * 64]);
        stage16(Vtptr + (size_t)(r1 + sub) * SEQ + ss * 8, &Vts[0][r1 * 64]);
    }

    for (int kt = 0; kt < SEQ / 64; ++kt) {
        __syncthreads();
        const int cur = kt & 1;
        if (kt + 1 < SEQ / 64) {
            const int nxt = cur ^ 1;
            const int r0 = w * 16, r1 = w * 16 + 8;
            const size_t ko = (size_t)((kt + 1) * 64);
            stage16(Kptr + (ko + r0 + sub) * DIM + ss * 8, &Ks[nxt][r0 * 64]);
            stage16(Kptr + (ko + r1 + sub) * DIM + ss * 8, &Ks[nxt][r1 * 64]);
            stage16(Vtptr + (size_t)(r0 + sub) * SEQ + ko + ss * 8, &Vts[nxt][r0 * 64]);
            stage16(Vtptr + (size_t)(r1 + sub) * SEQ + ko + ss * 8, &Vts[nxt][r1 * 64]);
        }

        const char* kbase = (const char*)Ks[cur];
        f32x16 S0 = {}, S1 = {};
#pragma unroll
        for (int df = 0; df < 4; ++df) {
            const int so = ((df * 2 + hi) ^ (l31 & 7)) << 4;
            bf16x8 k0 = *(const bf16x8*)(kbase + l31 * 128 + so);
            bf16x8 k1 = *(const bf16x8*)(kbase + (32 + l31) * 128 + so);
            S0 = __builtin_amdgcn_mfma_f32_32x32x16_bf16(k0, qf[df], S0, 0, 0, 0);
            S1 = __builtin_amdgcn_mfma_f32_32x32x16_bf16(k1, qf[df], S1, 0, 0, 0);
        }

        float p[32];
#pragma unroll
        for (int r = 0; r < 16; ++r) {
            p[r]      = __builtin_amdgcn_exp2f(S0[r]);
            p[16 + r] = __builtin_amdgcn_exp2f(S1[r]);
        }

        const unsigned long long bits = mbp[kt];
        if (bits != ~0ull) {
#pragma unroll
            for (int r = 0; r < 16; ++r) {
                const int key0 = (r & 3) + 8 * (r >> 2) + 4 * hi;
                p[r]      *= (float)((bits >> key0) & 1);
                p[16 + r] *= (float)((bits >> (32 + key0)) & 1);
            }
        }

#pragma unroll
        for (int r = 0; r < 32; ++r) lsum += p[r];

        bf16x8 pa[4];
#pragma unroll
        for (int krow = 0; krow < 2; ++krow) {
            const float* pp = &p[krow * 16];
            unsigned w01[4], w23[4];
#pragma unroll
            for (int a = 0; a < 4; ++a) {
                w01[a] = cvtpk(pp[4 * a + 0], pp[4 * a + 1]);
                w23[a] = cvtpk(pp[4 * a + 2], pp[4 * a + 3]);
            }
#pragma unroll
            for (int fh = 0; fh < 2; ++fh) {
                unsigned A0 = w01[2 * fh], B0 = w01[2 * fh + 1];
                unsigned A1 = w23[2 * fh], B1 = w23[2 * fh + 1];
                plswap(A0, B0);
                plswap(A1, B1);
                u32x4 tt = {A0, A1, B0, B1};
                union { u32x4 u; bf16x8 v; } cvt;
                cvt.u = tt;
                pa[krow * 2 + fh] = cvt.v;
            }
        }

        const char* vbase = (const char*)Vts[cur];
#pragma unroll
        for (int kf2 = 0; kf2 < 4; ++kf2) {
            const int so = ((kf2 * 2 + hi) ^ (l31 & 7)) << 4;
            bf16x8 v0 = *(const bf16x8*)(vbase + l31 * 128 + so);
            bf16x8 v1 = *(const bf16x8*)(vbase + (32 + l31) * 128 + so);
            ctx0 = __builtin_amdgcn_mfma_f32_32x32x16_bf16(pa[kf2], v0, ctx0, 0, 0, 0);
            ctx1 = __builtin_amdgcn_mfma_f32_32x32x16_bf16(pa[kf2], v1, ctx1, 0, 0, 0);
        }
    }

    lsum += __shfl_xor(lsum, 32);
    const float inv = 1.0f / lsum;

    const size_t orow0 = (size_t)(b * SEQ + qt * 128 + w * 32);
#pragma unroll
    for (int r = 0; r < 16; ++r) {
        const int q = (r & 3) + 8 * (r >> 2) + 4 * hi;
        const float invr = __shfl(inv, q);
        const size_t ro = (orow0 + q) * DIM + h * DPH;
        CTXb[ro + l31]      = f2bf(ctx0[r] * invr);
        CTXb[ro + 32 + l31] = f2bf(ctx1[r] * invr);
    }
}

// ---------------- launch ----------------
extern "C" void kernel_launch(void* const* d_in, const int* in_sizes, int n_in,
                              void* d_out, int out_size, void* d_ws, size_t ws_size,
                              hipStream_t stream)
{
    const float* x    = (const float*)d_in[0];
    const int*   mask = (const int*)d_in[1];
    const float* Wq   = (const float*)d_in[2];
    const float* bq   = (const float*)d_in[3];
    const float* Wk   = (const float*)d_in[4];
    const float* bk   = (const float*)d_in[5];
    const float* Wv   = (const float*)d_in[6];
    const float* bv   = (const float*)d_in[7];
    const float* Wo   = (const float*)d_in[8];
    const float* bo   = (const float*)d_in[9];
    const float* scale = (const float*)d_in[10];
    float* out = (float*)d_out;

    char* p = (char*)d_ws;
    unsigned short* Xb  = (unsigned short*)p; p += (size_t)MTOT * DIM * 2;
    unsigned short* Wqt = (unsigned short*)p; p += (size_t)DIM * DIM * 2;
    unsigned short* Wkt = (unsigned short*)p; p += (size_t)DIM * DIM * 2;
    unsigned short* Wvt = (unsigned short*)p; p += (size_t)DIM * DIM * 2;
    unsigned short* Wot = (unsigned short*)p; p += (size_t)DIM * DIM * 2;
    unsigned short* Qb  = (unsigned short*)p; p += (size_t)MTOT * DIM * 2;
    unsigned short* Kb  = (unsigned short*)p; p += (size_t)MTOT * DIM * 2;
    unsigned short* Vtb = (unsigned short*)p; p += (size_t)MTOT * DIM * 2;  // [b,h,d,seq]
    unsigned short* CTXb = (unsigned short*)p; p += (size_t)MTOT * DIM * 2;
    unsigned long long* MBits = (unsigned long long*)p;                      // 64 words

    cast_x<<<dim3(MTOT * DIM / 4 / 256), 256, 0, stream>>>(x, Xb);
    prep_w<<<dim3(32, 32, 4), 256, 0, stream>>>(Wq, Wk, Wv, Wo, Wqt, Wkt, Wvt, Wot);
    pack_mask<<<dim3(16), 256, 0, stream>>>(mask, MBits);
    qkv_gemm<<<dim3(8, 32, 3), 256, 0, stream>>>(
        Xb, Wqt, Wkt, Wvt, bq, bk, bv, scale, Qb, Kb, Vtb);
    attn<<<dim3(16, 16, 2), 256, 0, stream>>>(Qb, Kb, Vtb, MBits, CTXb);
    o_gemm<<<dim3(8, 32, 1), 256, 0, stream>>>(CTXb, Wot, bo, out);
}

// Round 9
// 237.025 us; speedup vs baseline: 1.0534x; 1.0534x over previous
//
#include <hip/hip_runtime.h>
#include <math.h>

#define SEQ 2048
#define DIM 1024
#define NH 16
#define DPH 64
#define MTOT 4096  // BS2 * SEQ

typedef __attribute__((ext_vector_type(8))) short bf16x8;
typedef __attribute__((ext_vector_type(4))) float f32x4;
typedef __attribute__((ext_vector_type(16))) float f32x16;
typedef __attribute__((ext_vector_type(4))) unsigned int u32x4;

__device__ __forceinline__ unsigned short f2bf(float f) {
    unsigned int u = __float_as_uint(f);
    return (unsigned short)((u + 0x7FFFu + ((u >> 16) & 1u)) >> 16);
}
__device__ __forceinline__ float bf2f(unsigned short h) {
    return __uint_as_float(((unsigned int)h) << 16);
}

__device__ __forceinline__ void stage16(const void* g, void* lds) {
    __builtin_amdgcn_global_load_lds((const __attribute__((address_space(1))) void*)g,
                                     (__attribute__((address_space(3))) void*)lds,
                                     16, 0, 0);
}

__device__ __forceinline__ unsigned cvtpk(float lo, float hi) {
    unsigned w;
    asm("v_cvt_pk_bf16_f32 %0, %1, %2" : "=v"(w) : "v"(lo), "v"(hi));
    return w;
}
// v_permlane32_swap_b32 A, B:  A' = {A_lo, B_lo}, B' = {A_hi, B_hi}
__device__ __forceinline__ void plswap(unsigned &a, unsigned &b) {
    asm("v_permlane32_swap_b32 %0, %1" : "+v"(a), "+v"(b));
}

// XCD-aware bijective remap (nb % 8 == 0). Dispatch order: x fastest.
__device__ __forceinline__ void xcd_remap(int gx, int gy, int gz,
                                          int &x, int &y, int &z)
{
    const int h = (blockIdx.z * gy + blockIdx.y) * gx + blockIdx.x;
    const int nb = gx * gy * gz;
    const int chunk = nb >> 3;
    const int l = (h & 7) * chunk + (h >> 3);
    const int P = gx * gz;
    y = l / P;
    const int r = l - y * P;
    z = r / gx;
    x = r - z * gx;
}

// ---------------- fused prep: W transpose-cast (z<4), X cast + mask pack (z==4) ----------------
__global__ __launch_bounds__(256) void prep_all(
    const float* __restrict__ X, unsigned short* __restrict__ Xb,
    const float* __restrict__ Wq, const float* __restrict__ Wk,
    const float* __restrict__ Wv, const float* __restrict__ Wo,
    unsigned short* __restrict__ Wqt, unsigned short* __restrict__ Wkt,
    unsigned short* __restrict__ Wvt, unsigned short* __restrict__ Wot,
    const int* __restrict__ mask, unsigned long long* __restrict__ MB)
{
    const int z = blockIdx.z;
    if (z < 4) {
        const float* W; unsigned short* Wt;
        switch (z) {
            case 0: W = Wq; Wt = Wqt; break;
            case 1: W = Wk; Wt = Wkt; break;
            case 2: W = Wv; Wt = Wvt; break;
            default: W = Wo; Wt = Wot; break;
        }
        __shared__ float T[32][33];
        const int t = threadIdx.x;
        const int bx = blockIdx.x & 31, by = blockIdx.x >> 5;
        const int kt0 = by * 32, nt0 = bx * 32;
        const int r = t >> 3, c4 = (t & 7) * 4;
        float4 v = *(const float4*)&W[(size_t)(kt0 + r) * DIM + nt0 + c4];
        T[r][c4 + 0] = v.x; T[r][c4 + 1] = v.y; T[r][c4 + 2] = v.z; T[r][c4 + 3] = v.w;
        __syncthreads();
        ushort4 o;
        o.x = f2bf(T[c4 + 0][r]);
        o.y = f2bf(T[c4 + 1][r]);
        o.z = f2bf(T[c4 + 2][r]);
        o.w = f2bf(T[c4 + 3][r]);
        *(ushort4*)&Wt[(size_t)(nt0 + r) * DIM + kt0 + c4] = o;
    } else {
        // cast X: 1024 blocks x 256 threads x 16 floats = 4M elems
        const size_t base = ((size_t)blockIdx.x * 256 + threadIdx.x) * 16;
#pragma unroll
        for (int q = 0; q < 4; ++q) {
            float4 v = *(const float4*)&X[base + q * 4];
            ushort4 o;
            o.x = f2bf(v.x); o.y = f2bf(v.y); o.z = f2bf(v.z); o.w = f2bf(v.w);
            *(ushort4*)&Xb[base + q * 4] = o;
        }
        if (blockIdx.x < 16) {
            const int w = blockIdx.x * 4 + (threadIdx.x >> 6);
            const int lane = threadIdx.x & 63;
            const int b = w >> 5, kt = w & 31;
            unsigned long long bits = __ballot(mask[b * SEQ + kt * 64 + lane] != 0);
            if (lane == 0) MB[w] = bits;
        }
    }
}

// ---------------- bf16 MFMA GEMM core, double-buffered 2-phase (R7-verified) ----------------
// mode 0: normalized bf16 out (per-head L2 norm; qs factor)
// mode 1: bf16 transposed V out [b,h,d,seq]
// mode 2: fp32 out + bias
__device__ __forceinline__ void gemm_core(
    const unsigned short* __restrict__ Ab, const unsigned short* __restrict__ Bt,
    const float* __restrict__ bias, unsigned short* __restrict__ Cb,
    float* __restrict__ Cf, int mode, int bx, int by, float qs)
{
    __shared__ __align__(16) unsigned short As[2][4096];
    __shared__ __align__(16) unsigned short Bs[2][4096];

    const int tid = threadIdx.x;
    const int l = tid & 63;
    const int w = tid >> 6;
    const int wm = w >> 1, wn = w & 1;
    const int lr = l & 15, lg = l >> 4;
    const int bm = by * 128;
    const int bn = bx * 128;

    const unsigned short* a_src0 = Ab + (size_t)(bm + (2 * w) * 16 + lr) * DIM + lg * 8;
    const unsigned short* a_src1 = Ab + (size_t)(bm + (2 * w + 1) * 16 + lr) * DIM + lg * 8;
    const unsigned short* b_src0 = Bt + (size_t)(bn + (2 * w) * 16 + lr) * DIM + lg * 8;
    const unsigned short* b_src1 = Bt + (size_t)(bn + (2 * w + 1) * 16 + lr) * DIM + lg * 8;

    f32x4 acc[4][4];
#pragma unroll
    for (int i = 0; i < 4; ++i)
#pragma unroll
        for (int j = 0; j < 4; ++j) acc[i][j] = (f32x4){0.f, 0.f, 0.f, 0.f};

    // prologue: stage K-step 0 into buf 0
    stage16(a_src0, &As[0][(2 * w) * 512]);
    stage16(a_src1, &As[0][(2 * w + 1) * 512]);
    stage16(b_src0, &Bs[0][(2 * w) * 512]);
    stage16(b_src1, &Bs[0][(2 * w + 1) * 512]);

    int t = 0;
    for (int kk = 0; kk < DIM; kk += 32) {
        __syncthreads();  // drains stage(buf t); prior reads of buf t^1 done
        if (kk + 32 < DIM) {
            const int nxt = t ^ 1;
            stage16(a_src0 + kk + 32, &As[nxt][(2 * w) * 512]);
            stage16(a_src1 + kk + 32, &As[nxt][(2 * w + 1) * 512]);
            stage16(b_src0 + kk + 32, &Bs[nxt][(2 * w) * 512]);
            stage16(b_src1 + kk + 32, &Bs[nxt][(2 * w + 1) * 512]);
        }
        bf16x8 aF[4], bF[4];
#pragma unroll
        for (int i = 0; i < 4; ++i) {
            aF[i] = *(const bf16x8*)&As[t][(wm * 4 + i) * 512 + l * 8];
            bF[i] = *(const bf16x8*)&Bs[t][(wn * 4 + i) * 512 + l * 8];
        }
#pragma unroll
        for (int i = 0; i < 4; ++i)
#pragma unroll
            for (int j = 0; j < 4; ++j)
                acc[i][j] = __builtin_amdgcn_mfma_f32_16x16x32_bf16(aF[i], bF[j], acc[i][j], 0, 0, 0);
        t ^= 1;
    }

    // bias add (bias[n] per column)
    float bvj[4];
#pragma unroll
    for (int j = 0; j < 4; ++j) bvj[j] = bias[bn + wn * 64 + j * 16 + lr];
#pragma unroll
    for (int i = 0; i < 4; ++i)
#pragma unroll
        for (int j = 0; j < 4; ++j)
#pragma unroll
            for (int p = 0; p < 4; ++p) acc[i][j][p] += bvj[j];

    if (mode == 0) {
        // fused per-head L2 norm: head = 64 cols = j regs x 16 lr lanes (within wave)
#pragma unroll
        for (int i = 0; i < 4; ++i) {
            float scl[4];
#pragma unroll
            for (int p = 0; p < 4; ++p) {
                float s = 0.f;
#pragma unroll
                for (int j = 0; j < 4; ++j) s = fmaf(acc[i][j][p], acc[i][j][p], s);
                s += __shfl_xor(s, 1);
                s += __shfl_xor(s, 2);
                s += __shfl_xor(s, 4);
                s += __shfl_xor(s, 8);
                scl[p] = qs / fmaxf(sqrtf(s), 1e-12f);
            }
            const int m0 = bm + wm * 64 + i * 16 + lg * 4;
#pragma unroll
            for (int j = 0; j < 4; ++j) {
                const int n = bn + wn * 64 + j * 16 + lr;
#pragma unroll
                for (int p = 0; p < 4; ++p)
                    Cb[(size_t)(m0 + p) * DIM + n] = f2bf(acc[i][j][p] * scl[p]);
            }
        }
    } else if (mode == 1) {
#pragma unroll
        for (int i = 0; i < 4; ++i) {
            const int m0 = bm + wm * 64 + i * 16 + lg * 4;
            const int b = m0 >> 11, s = m0 & 2047;
#pragma unroll
            for (int j = 0; j < 4; ++j) {
                const int n = bn + wn * 64 + j * 16 + lr;
                const int h = n >> 6, d = n & 63;
                ushort4 o;
                o.x = f2bf(acc[i][j][0]);
                o.y = f2bf(acc[i][j][1]);
                o.z = f2bf(acc[i][j][2]);
                o.w = f2bf(acc[i][j][3]);
                *(ushort4*)&Cb[((size_t)((b * NH + h) * DPH + d)) * SEQ + s] = o;
            }
        }
    } else {
#pragma unroll
        for (int i = 0; i < 4; ++i) {
            const int m0 = bm + wm * 64 + i * 16 + lg * 4;
#pragma unroll
            for (int j = 0; j < 4; ++j) {
                const int n = bn + wn * 64 + j * 16 + lr;
#pragma unroll
                for (int p = 0; p < 4; ++p)
                    Cf[(size_t)(m0 + p) * DIM + n] = acc[i][j][p];
            }
        }
    }
}

__global__ __launch_bounds__(256) void qkv_gemm(
    const unsigned short* __restrict__ Xb,
    const unsigned short* __restrict__ Wqt, const unsigned short* __restrict__ Wkt,
    const unsigned short* __restrict__ Wvt,
    const float* __restrict__ bq, const float* __restrict__ bk, const float* __restrict__ bv,
    const float* __restrict__ scale_p,
    unsigned short* __restrict__ Qb, unsigned short* __restrict__ Kb,
    unsigned short* __restrict__ Vtb)
{
    // 2D XCD super-tile: 8 XCDs = 2 xz-groups x 4 y-groups.
    // A(y-panel) fetched by 2 XCDs (16 MB), W(x,z-panel) by 4 XCDs (24 MB) -> ~40 MB total.
    int x, y, z;
    {
        const int h = (blockIdx.z * 32 + blockIdx.y) * 8 + blockIdx.x;  // 0..767
        const int xcd = h & 7;
        const int idx = h >> 3;            // 0..95
        const int xzg = xcd & 1, yg = xcd >> 1;
        const int lxz = idx % 12, ly = idx / 12;
        const int xz = xzg * 12 + lxz;     // 0..23
        x = xz & 7;
        z = xz >> 3;
        y = yg * 8 + ly;                   // 0..31
    }
    if (z == 0)
        gemm_core(Xb, Wqt, bq, Qb, nullptr, 0, x, y, scale_p[0] * 1.44269504088896340736f);
    else if (z == 1)
        gemm_core(Xb, Wkt, bk, Kb, nullptr, 0, x, y, 1.0f);
    else
        gemm_core(Xb, Wvt, bv, Vtb, nullptr, 1, x, y, 1.0f);
}

__global__ __launch_bounds__(256) void o_gemm(
    const unsigned short* __restrict__ Ab, const unsigned short* __restrict__ Wot,
    const float* __restrict__ bo, float* __restrict__ Out)
{
    int x, y, z;
    xcd_remap(8, 32, 1, x, y, z);
    gemm_core(Ab, Wot, bo, nullptr, Out, 2, x, y, 1.0f);
}

// ---------------- flash attention, 32x32x16 MFMA, swapped QK^T, no-max softmax ----------------
__global__ __launch_bounds__(256) void attn(
    const unsigned short* __restrict__ Qb, const unsigned short* __restrict__ Kb,
    const unsigned short* __restrict__ Vtb, const unsigned long long* __restrict__ MB,
    unsigned short* __restrict__ CTXb)
{
    __shared__ __align__(16) unsigned short Ks[2][4096];   // [key64][d64] swizzled
    __shared__ __align__(16) unsigned short Vts[2][4096];  // [d64][key64] swizzled

    const int tid = threadIdx.x;
    const int l = tid & 63;
    const int w = tid >> 6;
    const int l31 = l & 31;
    const int hi = l >> 5;

    // XCD remap: group the 16 q-tiles of each (head,batch) on one XCD
    int qt, h, b;
    {
        const int hh = (blockIdx.z * 16 + blockIdx.y) * 16 + blockIdx.x;
        const int ll = (hh & 7) * 64 + (hh >> 3);
        qt = ll & 15;
        const int g = ll >> 4;
        h = g & 15;
        b = g >> 4;
    }

    const size_t qrow = (size_t)(b * SEQ + qt * 128 + w * 32 + l31);
    bf16x8 qf[4];
#pragma unroll
    for (int df = 0; df < 4; ++df)
        qf[df] = *(const bf16x8*)&Qb[qrow * DIM + h * DPH + df * 16 + hi * 8];

    const int sub = l >> 3, ss = (l & 7) ^ sub;
    const unsigned short* Kptr  = Kb  + (size_t)(b * SEQ) * DIM + h * DPH;
    const unsigned short* Vtptr = Vtb + ((size_t)(b * NH + h) * DPH) * SEQ;
    const unsigned long long* mbp = MB + b * 32;

    f32x16 ctx0 = {}, ctx1 = {};
    float lsum = 0.f;

    {
        const int r0 = w * 16, r1 = w * 16 + 8;
        stage16(Kptr + (size_t)(r0 + sub) * DIM + ss * 8, &Ks[0][r0 * 64]);
        stage16(Kptr + (size_t)(r1 + sub) * DIM + ss * 8, &Ks[0][r1 * 64]);
        stage16(Vtptr + (size_t)(r0 + sub) * SEQ + ss * 8, &Vts[0][r0 * 64]);
        stage16(Vtptr + (size_t)(r1 + sub) * SEQ + ss * 8, &Vts[0][r1 * 64]);
    }

    for (int kt = 0; kt < SEQ / 64; ++kt) {
        __syncthreads();
        const int cur = kt & 1;
        if (kt + 1 < SEQ / 64) {
            const int nxt = cur ^ 1;
            const int r0 = w * 16, r1 = w * 16 + 8;
            const size_t ko = (size_t)((kt + 1) * 64);
            stage16(Kptr + (ko + r0 + sub) * DIM + ss * 8, &Ks[nxt][r0 * 64]);
            stage16(Kptr + (ko + r1 + sub) * DIM + ss * 8, &Ks[nxt][r1 * 64]);
            stage16(Vtptr + (size_t)(r0 + sub) * SEQ + ko + ss * 8, &Vts[nxt][r0 * 64]);
            stage16(Vtptr + (size_t)(r1 + sub) * SEQ + ko + ss * 8, &Vts[nxt][r1 * 64]);
        }

        const char* kbase = (const char*)Ks[cur];
        f32x16 S0 = {}, S1 = {};
        __builtin_amdgcn_s_setprio(1);
#pragma unroll
        for (int df = 0; df < 4; ++df) {
            const int so = ((df * 2 + hi) ^ (l31 & 7)) << 4;
            bf16x8 k0 = *(const bf16x8*)(kbase + l31 * 128 + so);
            bf16x8 k1 = *(const bf16x8*)(kbase + (32 + l31) * 128 + so);
            S0 = __builtin_amdgcn_mfma_f32_32x32x16_bf16(k0, qf[df], S0, 0, 0, 0);
            S1 = __builtin_amdgcn_mfma_f32_32x32x16_bf16(k1, qf[df], S1, 0, 0, 0);
        }
        __builtin_amdgcn_s_setprio(0);

        float p[32];
#pragma unroll
        for (int r = 0; r < 16; ++r) {
            p[r]      = __builtin_amdgcn_exp2f(S0[r]);
            p[16 + r] = __builtin_amdgcn_exp2f(S1[r]);
        }

        const unsigned long long bits = mbp[kt];
        if (bits != ~0ull) {
#pragma unroll
            for (int r = 0; r < 16; ++r) {
                const int key0 = (r & 3) + 8 * (r >> 2) + 4 * hi;
                p[r]      *= (float)((bits >> key0) & 1);
                p[16 + r] *= (float)((bits >> (32 + key0)) & 1);
            }
        }

#pragma unroll
        for (int r = 0; r < 32; ++r) lsum += p[r];

        bf16x8 pa[4];
#pragma unroll
        for (int krow = 0; krow < 2; ++krow) {
            const float* pp = &p[krow * 16];
            unsigned w01[4], w23[4];
#pragma unroll
            for (int a = 0; a < 4; ++a) {
                w01[a] = cvtpk(pp[4 * a + 0], pp[4 * a + 1]);
                w23[a] = cvtpk(pp[4 * a + 2], pp[4 * a + 3]);
            }
#pragma unroll
            for (int fh = 0; fh < 2; ++fh) {
                unsigned A0 = w01[2 * fh], B0 = w01[2 * fh + 1];
                unsigned A1 = w23[2 * fh], B1 = w23[2 * fh + 1];
                plswap(A0, B0);
                plswap(A1, B1);
                u32x4 tt = {A0, A1, B0, B1};
                union { u32x4 u; bf16x8 v; } cvt;
                cvt.u = tt;
                pa[krow * 2 + fh] = cvt.v;
            }
        }

        const char* vbase = (const char*)Vts[cur];
        __builtin_amdgcn_s_setprio(1);
#pragma unroll
        for (int kf2 = 0; kf2 < 4; ++kf2) {
            const int so = ((kf2 * 2 + hi) ^ (l31 & 7)) << 4;
            bf16x8 v0 = *(const bf16x8*)(vbase + l31 * 128 + so);
            bf16x8 v1 = *(const bf16x8*)(vbase + (32 + l31) * 128 + so);
            ctx0 = __builtin_amdgcn_mfma_f32_32x32x16_bf16(pa[kf2], v0, ctx0, 0, 0, 0);
            ctx1 = __builtin_amdgcn_mfma_f32_32x32x16_bf16(pa[kf2], v1, ctx1, 0, 0, 0);
        }
        __builtin_amdgcn_s_setprio(0);
    }

    lsum += __shfl_xor(lsum, 32);
    const float inv = 1.0f / lsum;

    const size_t orow0 = (size_t)(b * SEQ + qt * 128 + w * 32);
#pragma unroll
    for (int r = 0; r < 16; ++r) {
        const int q = (r & 3) + 8 * (r >> 2) + 4 * hi;
        const float invr = __shfl(inv, q);
        const size_t ro = (orow0 + q) * DIM + h * DPH;
        CTXb[ro + l31]      = f2bf(ctx0[r] * invr);
        CTXb[ro + 32 + l31] = f2bf(ctx1[r] * invr);
    }
}

// ---------------- launch ----------------
extern "C" void kernel_launch(void* const* d_in, const int* in_sizes, int n_in,
                              void* d_out, int out_size, void* d_ws, size_t ws_size,
                              hipStream_t stream)
{
    const float* x    = (const float*)d_in[0];
    const int*   mask = (const int*)d_in[1];
    const float* Wq   = (const float*)d_in[2];
    const float* bq   = (const float*)d_in[3];
    const float* Wk   = (const float*)d_in[4];
    const float* bk   = (const float*)d_in[5];
    const float* Wv   = (const float*)d_in[6];
    const float* bv   = (const float*)d_in[7];
    const float* Wo   = (const float*)d_in[8];
    const float* bo   = (const float*)d_in[9];
    const float* scale = (const float*)d_in[10];
    float* out = (float*)d_out;

    char* p = (char*)d_ws;
    unsigned short* Xb  = (unsigned short*)p; p += (size_t)MTOT * DIM * 2;
    unsigned short* Wqt = (unsigned short*)p; p += (size_t)DIM * DIM * 2;
    unsigned short* Wkt = (unsigned short*)p; p += (size_t)DIM * DIM * 2;
    unsigned short* Wvt = (unsigned short*)p; p += (size_t)DIM * DIM * 2;
    unsigned short* Wot = (unsigned short*)p; p += (size_t)DIM * DIM * 2;
    unsigned short* Qb  = (unsigned short*)p; p += (size_t)MTOT * DIM * 2;
    unsigned short* Kb  = (unsigned short*)p; p += (size_t)MTOT * DIM * 2;
    unsigned short* Vtb = (unsigned short*)p; p += (size_t)MTOT * DIM * 2;  // [b,h,d,seq]
    unsigned short* CTXb = (unsigned short*)p; p += (size_t)MTOT * DIM * 2;
    unsigned long long* MBits = (unsigned long long*)p;                      // 64 words

    prep_all<<<dim3(1024, 1, 5), 256, 0, stream>>>(
        x, Xb, Wq, Wk, Wv, Wo, Wqt, Wkt, Wvt, Wot, mask, MBits);
    qkv_gemm<<<dim3(8, 32, 3), 256, 0, stream>>>(
        Xb, Wqt, Wkt, Wvt, bq, bk, bv, scale, Qb, Kb, Vtb);
    attn<<<dim3(16, 16, 2), 256, 0, stream>>>(Qb, Kb, Vtb, MBits, CTXb);
    o_gemm<<<dim3(8, 32, 1), 256, 0, stream>>>(CTXb, Wot, bo, out);
}